// Round 7
// baseline (1850.865 us; speedup 1.0000x reference)
//
#include <hip/hip_runtime.h>

#define Dn 512
#define Bn 32
#define Tn 2048
#define BT 65536   // Bn*Tn
#define NCHUNK 64  // K-chunks for gram (64*10 = 640 blocks ~ 2.5/CU)
#define CHUNK_K 1024  // 65536/64

typedef unsigned short u16;
typedef __attribute__((ext_vector_type(8))) short short8;   // 8 bf16 = 4 VGPRs (MFMA A/B frag)
typedef __attribute__((ext_vector_type(4))) float floatx4;  // MFMA C/D frag

__device__ __forceinline__ u16 f2bf(float f) {
    unsigned u = __float_as_uint(f);
    unsigned r = (u + 0x7FFFu + ((u >> 16) & 1u)) >> 16;    // RNE
    return (u16)r;
}
__device__ __forceinline__ float bf2f(u16 s) { return __uint_as_float(((unsigned)s) << 16); }

// async global->LDS, 16B per lane; LDS dest is wave-uniform base + lane*16 (m104)
#define GLL(gp, sp) __builtin_amdgcn_global_load_lds( \
    (const __attribute__((address_space(1))) void*)(gp), \
    (__attribute__((address_space(3))) void*)(sp), 16, 0, 0)

// Repeat lists. r6 lesson: batch width IS register pressure -- 64-wide shuffle
// or LDS-read batches + 64 named accumulators = >128 live = scratch spill in a
// serial loop (1490us). Halved (32-wide) batches bound peak liveness ~100.
#define REP64(X) X(0) X(1) X(2) X(3) X(4) X(5) X(6) X(7) X(8) X(9) X(10) X(11) X(12) X(13) X(14) X(15) \
    X(16) X(17) X(18) X(19) X(20) X(21) X(22) X(23) X(24) X(25) X(26) X(27) X(28) X(29) X(30) X(31) \
    X(32) X(33) X(34) X(35) X(36) X(37) X(38) X(39) X(40) X(41) X(42) X(43) X(44) X(45) X(46) X(47) \
    X(48) X(49) X(50) X(51) X(52) X(53) X(54) X(55) X(56) X(57) X(58) X(59) X(60) X(61) X(62) X(63)
// halves of 0..63 (for factor shuffle batches)
#define REPJH1(OP, K) OP(K,0) OP(K,1) OP(K,2) OP(K,3) OP(K,4) OP(K,5) OP(K,6) OP(K,7) OP(K,8) OP(K,9) \
    OP(K,10) OP(K,11) OP(K,12) OP(K,13) OP(K,14) OP(K,15) OP(K,16) OP(K,17) OP(K,18) OP(K,19) \
    OP(K,20) OP(K,21) OP(K,22) OP(K,23) OP(K,24) OP(K,25) OP(K,26) OP(K,27) OP(K,28) OP(K,29) \
    OP(K,30) OP(K,31)
#define REPJH2(OP, K) OP(K,32) OP(K,33) OP(K,34) OP(K,35) OP(K,36) OP(K,37) OP(K,38) OP(K,39) \
    OP(K,40) OP(K,41) OP(K,42) OP(K,43) OP(K,44) OP(K,45) OP(K,46) OP(K,47) OP(K,48) OP(K,49) \
    OP(K,50) OP(K,51) OP(K,52) OP(K,53) OP(K,54) OP(K,55) OP(K,56) OP(K,57) OP(K,58) OP(K,59) \
    OP(K,60) OP(K,61) OP(K,62) OP(K,63)
// 64 (M, Mq=M/4, e=M%4) triples, quarter lists (global Mq 0..15)
#define REPQA(OP, C) OP(C,0,0,0) OP(C,1,0,1) OP(C,2,0,2) OP(C,3,0,3) OP(C,4,1,0) OP(C,5,1,1) OP(C,6,1,2) OP(C,7,1,3) \
    OP(C,8,2,0) OP(C,9,2,1) OP(C,10,2,2) OP(C,11,2,3) OP(C,12,3,0) OP(C,13,3,1) OP(C,14,3,2) OP(C,15,3,3)
#define REPQB(OP, C) OP(C,16,4,0) OP(C,17,4,1) OP(C,18,4,2) OP(C,19,4,3) OP(C,20,5,0) OP(C,21,5,1) OP(C,22,5,2) OP(C,23,5,3) \
    OP(C,24,6,0) OP(C,25,6,1) OP(C,26,6,2) OP(C,27,6,3) OP(C,28,7,0) OP(C,29,7,1) OP(C,30,7,2) OP(C,31,7,3)
#define REPQC(OP, C) OP(C,32,8,0) OP(C,33,8,1) OP(C,34,8,2) OP(C,35,8,3) OP(C,36,9,0) OP(C,37,9,1) OP(C,38,9,2) OP(C,39,9,3) \
    OP(C,40,10,0) OP(C,41,10,1) OP(C,42,10,2) OP(C,43,10,3) OP(C,44,11,0) OP(C,45,11,1) OP(C,46,11,2) OP(C,47,11,3)
#define REPQD(OP, C) OP(C,48,12,0) OP(C,49,12,1) OP(C,50,12,2) OP(C,51,12,3) OP(C,52,13,0) OP(C,53,13,1) OP(C,54,13,2) OP(C,55,13,3) \
    OP(C,56,14,0) OP(C,57,14,1) OP(C,58,14,2) OP(C,59,14,3) OP(C,60,15,0) OP(C,61,15,1) OP(C,62,15,2) OP(C,63,15,3)
#define REPQ(OP, C) REPQA(OP, C) REPQB(OP, C) REPQC(OP, C) REPQD(OP, C)
// 16 (Q, 4Q, 4Q+1, 4Q+2, 4Q+3) groups
#define REPW(OP) OP(0,0,1,2,3) OP(1,4,5,6,7) OP(2,8,9,10,11) OP(3,12,13,14,15) OP(4,16,17,18,19) \
    OP(5,20,21,22,23) OP(6,24,25,26,27) OP(7,28,29,30,31) OP(8,32,33,34,35) OP(9,36,37,38,39) \
    OP(10,40,41,42,43) OP(11,44,45,46,47) OP(12,48,49,50,51) OP(13,52,53,54,55) OP(14,56,57,58,59) \
    OP(15,60,61,62,63)

// ---------------------------------------------------------------------------
// 0) zero mu accumulator (ws is poisoned by harness; atomics need 0-init)
// ---------------------------------------------------------------------------
__global__ __launch_bounds__(256) void k_zero(float* __restrict__ mu) {
    floatx4 z = {0.f, 0.f, 0.f, 0.f};
    ((floatx4*)mu)[blockIdx.x * 256 + threadIdx.x] = z;
}

// ---------------------------------------------------------------------------
// 1) x[b][t][d] (f32) -> Xt[d][b*Tn+t] (bf16), LDS 64x64 tile transpose.
//    Fused per-(b,d) t-sums atomicAdd'ed into mu (mu holds SUMS over t).
// ---------------------------------------------------------------------------
__global__ __launch_bounds__(256) void k_transpose(const float* __restrict__ x,
                                                   u16* __restrict__ Xt,
                                                   float* __restrict__ mu) {
    int tt = blockIdx.x;   // t-tile 0..31
    int dt = blockIdx.y;   // d-tile 0..7
    int b  = blockIdx.z;   // 0..31
    __shared__ u16 sT[64][68];  // [d][t], padded
    int tid = threadIdx.x;
    int row = tid >> 4;            // 0..15 (t)
    int c4  = (tid & 15) * 4;      // 0..60 (d)
    const float* src = x + ((long)b * Tn + (long)tt * 64) * Dn + dt * 64;
#pragma unroll
    for (int q = 0; q < 4; q++) {
        int r = row + q * 16;
        floatx4 v = *(const floatx4*)(src + (long)r * Dn + c4);
        sT[c4 + 0][r] = f2bf(v[0]);
        sT[c4 + 1][r] = f2bf(v[1]);
        sT[c4 + 2][r] = f2bf(v[2]);
        sT[c4 + 3][r] = f2bf(v[3]);
    }
    __syncthreads();
    int drow = tid >> 3;           // 0..31 (d)
    int koff = (tid & 7) * 8;      // 0..56 (t)
    long kout = (long)b * Tn + (long)tt * 64 + koff;
#pragma unroll
    for (int p = 0; p < 2; p++) {
        int dr = drow + p * 32;
        u16 tmp[8];
        float s = 0.f;
#pragma unroll
        for (int j = 0; j < 8; j++) {
            tmp[j] = sT[dr][koff + j];
            s += bf2f(tmp[j]);
        }
        *(short8*)(Xt + (long)(dt * 64 + dr) * BT + kout) = *(short8*)tmp;
        s += __shfl_down(s, 4, 64);
        s += __shfl_down(s, 2, 64);
        s += __shfl_down(s, 1, 64);
        if ((tid & 7) == 0) atomicAdd(mu + b * 512 + dt * 64 + dr, s);
    }
}

// ---------------------------------------------------------------------------
// 2) Gram partials: partial[chunk][d][e] = sum_{k in chunk} Xt[d][k]*Xt[e][k]
// ---------------------------------------------------------------------------
__global__ __launch_bounds__(256, 3) void k_gram(const u16* __restrict__ Xt,
                                                 float* __restrict__ partial) {
    int chunk = blockIdx.x;             // 0..63 (K-chunk of 1024)
    int pos = blockIdx.y;               // 0..9 upper-block-triangle positions
    int di = (pos < 4) ? 0 : (pos < 7) ? 1 : (pos < 9) ? 2 : 3;
    int start = di * 4 - (di * (di - 1)) / 2;   // 0,4,7,9
    int ei = di + (pos - start);
    int d0 = di * 128, e0 = ei * 128;

    __shared__ u16 sA[128 * 32];
    __shared__ u16 sB[128 * 32];
    int tid = threadIdx.x;
    int w = tid >> 6, l = tid & 63;
    int wm = w & 1, wn = w >> 1;        // 2x2 waves over 128x128
    long kbase = (long)chunk * CHUNK_K;
    int srow = w * 16 + (l >> 2);
    int sk = (l & 3) * 8;
    const u16* gA0 = Xt + (long)(d0 + srow) * BT + kbase + sk;
    const u16* gA1 = gA0 + 64l * BT;
    const u16* gB0 = Xt + (long)(e0 + srow) * BT + kbase + sk;
    const u16* gB1 = gB0 + 64l * BT;
    u16* sA0 = sA + (w * 16) * 32;      // wave-uniform LDS bases
    u16* sA1 = sA0 + 64 * 32;
    u16* sB0 = sB + (w * 16) * 32;
    u16* sB1 = sB0 + 64 * 32;
    int m = l & 15, g = l >> 4;
    const u16* fA = sA + (wm * 64 + m) * 32 + g * 8;
    const u16* fB = sB + (wn * 64 + m) * 32 + g * 8;

    floatx4 acc[4][4] = {};
    for (int kk = 0; kk < CHUNK_K; kk += 32) {
        GLL(gA0 + kk, sA0);
        GLL(gA1 + kk, sA1);
        GLL(gB0 + kk, sB0);
        GLL(gB1 + kk, sB1);
        __syncthreads();   // drains vmcnt -> staged data visible
        short8 af[4], bfv[4];
#pragma unroll
        for (int i = 0; i < 4; i++) af[i] = *(const short8*)(fA + i * 16 * 32);
#pragma unroll
        for (int j = 0; j < 4; j++) bfv[j] = *(const short8*)(fB + j * 16 * 32);
#pragma unroll
        for (int i = 0; i < 4; i++)
#pragma unroll
            for (int j = 0; j < 4; j++)
                acc[i][j] = __builtin_amdgcn_mfma_f32_16x16x32_bf16(af[i], bfv[j], acc[i][j], 0, 0, 0);
        __syncthreads();
    }
    float* P = partial + (long)chunk * (512l * 512);
    int col = l & 15, rowg = (l >> 4) * 4;   // C/D: col=lane&15, row=(lane>>4)*4+reg
#pragma unroll
    for (int i = 0; i < 4; i++)
#pragma unroll
        for (int j = 0; j < 4; j++) {
            int rr = d0 + wm * 64 + i * 16 + rowg;
            int cc = e0 + wn * 64 + j * 16 + col;
#pragma unroll
            for (int r = 0; r < 4; r++) P[(long)(rr + r) * 512 + cc] = acc[i][j][r];
        }
}

// ---------------------------------------------------------------------------
// 3) cov assemble (1024 blocks: MLP hides the mirror-read latency; r3 lesson)
// ---------------------------------------------------------------------------
__global__ __launch_bounds__(256) void k_assemble(const float* __restrict__ partial,
                                                  const float* __restrict__ mu,
                                                  float* __restrict__ A) {
    int d = blockIdx.y;
    int e = blockIdx.x * 256 + threadIdx.x;
    int bd = d >> 7, be = e >> 7;
    long idx = (bd <= be) ? ((long)d * 512 + e) : ((long)e * 512 + d);
    float s = 0.f;
#pragma unroll
    for (int c = 0; c < NCHUNK; c++) s += partial[c * (512l * 512) + idx];
    float msum = 0.f;
#pragma unroll
    for (int b = 0; b < 32; b++) msum += mu[b * 512 + d] * mu[b * 512 + e];
    A[(long)d * 512 + e] = (s - msum * (1.0f / Tn)) * (1.0f / ((Tn - 1.0f) * Bn));
}

// ---------------------------------------------------------------------------
// 4) SINGLE-WORKGROUP Cholesky, register-budget-correct (r6 fix):
//    - wave 0 ALONE factors the 64x64 diag in named regs, shuffle batches
//      HALVED (32 temps): peak ~100 VGPR. Publishes L11+inv to LDS sD.
//    - waves 1..nb preload their TRSM stripe (they skip the factor branch ->
//      loads overlap wave0's factor; a## not live at factor program point).
//    - TRSM reads L11 rows from sD in HALVED b128 batches (32 floats live):
//      peak ~100 VGPR. No r##+a## double working set (r6's 128-reg spill).
//    - trailing update: 2x256-thread groups, lockstep rounds (r6-proven).
// ---------------------------------------------------------------------------
__global__ __launch_bounds__(512, 2) void k_chol(float* __restrict__ A) {
    __shared__ float sD[64 * 68 + 64];   // L11 rows (stride 68) + sInv tail
    __shared__ float sU[16640];          // 2 groups x (sI[64*65] + sJ[64*65])
    const int tid = threadIdx.x;
    const int lane = tid & 63;
    const int wave = tid >> 6;    // 0..7
    const int grp = tid >> 8;     // 0..1
    const int gtid = tid & 255;
    float* const sInvp = sD + 64 * 68;
    const floatx4 z4 = {0.f, 0.f, 0.f, 0.f};

    for (int kb = 0; kb < 8; kb++) {
        const int k0 = kb * 64;
        const int nb = 7 - kb;

        // ======== wave 0: factor diag, write diag to A, publish to LDS ======
        if (wave == 0) {
            const float* Dr = A + (long)(k0 + lane) * 512 + k0;
#define LDV(Q,A0,A1,A2,A3) floatx4 v##Q = *(const floatx4*)(Dr + 4*(Q));
            REPW(LDV)
#undef LDV
#define DECR(C,M,Mq,e) float r##M = v##Mq[(e)];
            REPQ(DECR, 0)
#undef DECR
            float vinv = 0.f;
#define SH1(K,J) float t##J = ((J) > (K)) ? __shfl(lik, (J), 64) : 0.0f;
#define FM1(K,J) if ((J) > (K)) r##J = fmaf(nlik, t##J, r##J);
#define STEP(K) { float akk = __shfl(r##K, (K), 64); float sd = sqrtf(akk); \
    float inv = 1.0f / sd; float lik = (lane == (K)) ? sd : r##K * inv; \
    r##K = lik; if (lane == (K)) vinv = inv; float nlik = -lik; \
    { REPJH1(SH1, K) REPJH1(FM1, K) } { REPJH2(SH1, K) REPJH2(FM1, K) } }
            REP64(STEP)
#undef STEP
#undef FM1
#undef SH1
            // diag writeback (junk upper never read downstream)
            float* W = A + (long)(k0 + lane) * 512 + k0;
#define STW(Q,A0,A1,A2,A3) { floatx4 w; w[0]=r##A0; w[1]=r##A1; w[2]=r##A2; w[3]=r##A3; \
    *(floatx4*)(W + 4*(Q)) = w; *(floatx4*)(sD + lane * 68 + 4*(Q)) = w; }
            REPW(STW)
#undef STW
            sInvp[lane] = vinv;
        }

        // ======== waves 1..nb: preload stripe rows (overlaps factor) ========
        // (declared at this scope so they stay live across the barrier; NOT
        //  live during the factor block above -> no pressure interaction)
        if (wave >= 1 && wave <= nb) {
            const int rbase = k0 + 64 + (wave - 1) * 64;
            const float* R = A + (long)(rbase + lane) * 512 + k0;
#define LDA(Q,A0,A1,A2,A3) floatx4 u##Q = *(const floatx4*)(R + 4*(Q));
            REPW(LDA)
#undef LDA
#define DECA(C,M,Mq,e) float a##M = u##Mq[(e)];
            REPQ(DECA, 0)
#undef DECA
            __syncthreads();   // sD/sInv published
            // ---- TRSM: 64 steps, halved uniform b128 reads of L11 row C ----
#define TLD(C,Q) floatx4 g##Q = ((C) > 4*(Q)) ? *(const floatx4*)(sD + (C) * 68 + 4*(Q)) : z4;
#define TFL(C,M,Mq,e) if ((M) < (C)) acc##e = fmaf(a##M, g##Mq[(e)], acc##e);
#define TSTEP(C) { float acc0 = 0.f, acc1 = 0.f, acc2 = 0.f, acc3 = 0.f; \
    { TLD(C,0) TLD(C,1) TLD(C,2) TLD(C,3) TLD(C,4) TLD(C,5) TLD(C,6) TLD(C,7) \
      REPQA(TFL, C) REPQB(TFL, C) } \
    { TLD(C,8) TLD(C,9) TLD(C,10) TLD(C,11) TLD(C,12) TLD(C,13) TLD(C,14) TLD(C,15) \
      REPQC(TFL, C) REPQD(TFL, C) } \
    a##C = (a##C - ((acc0 + acc1) + (acc2 + acc3))) * sInvp[(C)]; }
            REP64(TSTEP)
#undef TSTEP
#undef TFL
#undef TLD
            const int rb2 = k0 + 64 + (wave - 1) * 64;
            float* Wr = A + (long)(rb2 + lane) * 512 + k0;
#define STA(Q,A0,A1,A2,A3) { floatx4 w; w[0]=a##A0; w[1]=a##A1; w[2]=a##A2; w[3]=a##A3; \
    *(floatx4*)(Wr + 4*(Q)) = w; }
            REPW(STA)
#undef STA
        } else {
            __syncthreads();   // matching barrier for wave0 and idle waves
        }
        __syncthreads();       // TRSM writes to A visible (same CU)

        // ======== trailing update: A22 -= L21 L21^T, 2 tiles per round ======
        const int tiles = nb * (nb + 1) / 2;
        const int rounds = (tiles + 1) >> 1;
        for (int rd = 0; rd < rounds; rd++) {
            int t = rd * 2 + grp;
            int ti = 0, tj = 0;
            if (t < tiles) {
                int idx = t;
                while (idx > ti) { idx -= ti + 1; ti++; }
                tj = idx;
            }
            int r0 = k0 + 64 + ti * 64, c0 = k0 + 64 + tj * 64;
            float* sI = &sU[grp * 8320];
            float* sJ = &sU[grp * 8320 + 4160];
            if (t < tiles) {
                int row = gtid >> 4, c4 = (gtid & 15) * 4;
#pragma unroll
                for (int q = 0; q < 4; q++) {
                    int rr = row + q * 16;
                    *(floatx4*)&sI[rr * 65 + c4] = *(const floatx4*)(A + (long)(r0 + rr) * 512 + k0 + c4);
                    *(floatx4*)&sJ[rr * 65 + c4] = *(const floatx4*)(A + (long)(c0 + rr) * 512 + k0 + c4);
                }
            }
            __syncthreads();
            if (t < tiles) {
                int ri = (gtid >> 4) * 4, cj = (gtid & 15) * 4;
                float acc[4][4] = {};
                for (int k = 0; k < 64; k += 4) {
                    floatx4 av[4], bv[4];
#pragma unroll
                    for (int ii = 0; ii < 4; ii++) av[ii] = *(const floatx4*)&sI[(ri + ii) * 65 + k];
#pragma unroll
                    for (int jj = 0; jj < 4; jj++) bv[jj] = *(const floatx4*)&sJ[(cj + jj) * 65 + k];
#pragma unroll
                    for (int ii = 0; ii < 4; ii++)
#pragma unroll
                        for (int jj = 0; jj < 4; jj++)
#pragma unroll
                            for (int q = 0; q < 4; q++)
                                acc[ii][jj] = fmaf(av[ii][q], bv[jj][q], acc[ii][jj]);
                }
#pragma unroll
                for (int ii = 0; ii < 4; ii++) {
                    float* dst = A + (long)(r0 + ri + ii) * 512 + c0 + cj;
                    floatx4 old = *(const floatx4*)dst;
#pragma unroll
                    for (int jj = 0; jj < 4; jj++) old[jj] -= acc[ii][jj];
                    *(floatx4*)dst = old;
                }
            }
            __syncthreads();   // compute reads done before next round's staging
        }
    }
}

// ---------------------------------------------------------------------------
// 5) out[i][d] = mean[d] + sum_{e<=d} z[i][e] * L[d][e]
//    mu holds t-SUMS: mean[d] = sum_b mu[b,d] / (B*T)
// ---------------------------------------------------------------------------
__global__ __launch_bounds__(512) void k_output(const float* __restrict__ z,
                                                const float* __restrict__ A,
                                                const float* __restrict__ mu,
                                                float* __restrict__ out) {
    int i = blockIdx.x, d = threadIdx.x;
    __shared__ float sz[512];
    sz[d] = z[(long)i * 512 + d];
    __syncthreads();
    float mean = 0.f;
#pragma unroll
    for (int b = 0; b < 32; b++) mean += mu[b * 512 + d];
    mean *= (1.0f / (32.0f * 2048.0f));
    const float* Lr = A + (long)d * 512;
    float acc = 0.f;
    int dmax = d + 1;
    int e4 = dmax & ~3;
    for (int e = 0; e < e4; e += 4) {
        floatx4 l = *(const floatx4*)(Lr + e);
        acc += l[0] * sz[e] + l[1] * sz[e + 1] + l[2] * sz[e + 2] + l[3] * sz[e + 3];
    }
    for (int e = e4; e < dmax; e++) acc += Lr[e] * sz[e];
    out[(long)i * 512 + d] = mean + acc;
}

// ---------------------------------------------------------------------------
extern "C" void kernel_launch(void* const* d_in, const int* in_sizes, int n_in,
                              void* d_out, int out_size, void* d_ws, size_t ws_size,
                              hipStream_t stream) {
    const float* x = (const float*)d_in[0];
    const float* z = (const float*)d_in[1];
    float* out = (float*)d_out;
    char* ws = (char*)d_ws;
    // ws layout: Xt 67108864 | mu 65536 | partial 67108864 | A 1048576
    u16* Xt = (u16*)ws;
    float* mu = (float*)(ws + 67108864);
    float* partial = (float*)(ws + 67108864 + 65536);
    float* A = (float*)(ws + 67108864 + 65536 + 67108864);

    k_zero<<<16, 256, 0, stream>>>(mu);
    k_transpose<<<dim3(32, 8, 32), 256, 0, stream>>>(x, Xt, mu);
    k_gram<<<dim3(NCHUNK, 10), 256, 0, stream>>>(Xt, partial);
    k_assemble<<<dim3(2, 512), 256, 0, stream>>>(partial, mu, A);
    k_chol<<<1, 512, 0, stream>>>(A);
    k_output<<<32, 512, 0, stream>>>(z, A, mu, out);
}

// Round 8
// 574.827 us; speedup vs baseline: 3.2199x; 3.2199x over previous
//
#include <hip/hip_runtime.h>

#define Dn 512
#define Bn 32
#define Tn 2048
#define BT 65536   // Bn*Tn
#define NCHUNK 64  // K-chunks for gram (64*10 = 640 blocks ~ 2.5/CU)
#define CHUNK_K 1024  // 65536/64

typedef unsigned short u16;
typedef __attribute__((ext_vector_type(8))) short short8;   // 8 bf16 = 4 VGPRs (MFMA A/B frag)
typedef __attribute__((ext_vector_type(4))) float floatx4;  // MFMA C/D frag

__device__ __forceinline__ u16 f2bf(float f) {
    unsigned u = __float_as_uint(f);
    unsigned r = (u + 0x7FFFu + ((u >> 16) & 1u)) >> 16;    // RNE
    return (u16)r;
}
__device__ __forceinline__ float bf2f(u16 s) { return __uint_as_float(((unsigned)s) << 16); }

// async global->LDS, 16B per lane; LDS dest is wave-uniform base + lane*16 (m104)
#define GLL(gp, sp) __builtin_amdgcn_global_load_lds( \
    (const __attribute__((address_space(1))) void*)(gp), \
    (__attribute__((address_space(3))) void*)(sp), 16, 0, 0)

// Uniform broadcast from a compile-time lane: v_readlane -> SGPR, consumed as
// the single allowed SGPR operand of v_fma. NO LDS pipe, no ds_bpermute.
// (r6/r7 lesson: __shfl = ds_bpermute = LDS pipe; with 64/step x 512 steps the
//  LDS pipe + its latency dominated the whole Cholesky.)
#define RLF(x, L) __uint_as_float(__builtin_amdgcn_readlane(__float_as_uint(x), (L)))

// Repeat lists (named scalars, not arrays -> no scratch).
#define REP64(X) X(0) X(1) X(2) X(3) X(4) X(5) X(6) X(7) X(8) X(9) X(10) X(11) X(12) X(13) X(14) X(15) \
    X(16) X(17) X(18) X(19) X(20) X(21) X(22) X(23) X(24) X(25) X(26) X(27) X(28) X(29) X(30) X(31) \
    X(32) X(33) X(34) X(35) X(36) X(37) X(38) X(39) X(40) X(41) X(42) X(43) X(44) X(45) X(46) X(47) \
    X(48) X(49) X(50) X(51) X(52) X(53) X(54) X(55) X(56) X(57) X(58) X(59) X(60) X(61) X(62) X(63)
// halves of 0..63 (factor broadcast batches; bounds SGPR temp liveness to 32)
#define REPJH1(OP, K) OP(K,0) OP(K,1) OP(K,2) OP(K,3) OP(K,4) OP(K,5) OP(K,6) OP(K,7) OP(K,8) OP(K,9) \
    OP(K,10) OP(K,11) OP(K,12) OP(K,13) OP(K,14) OP(K,15) OP(K,16) OP(K,17) OP(K,18) OP(K,19) \
    OP(K,20) OP(K,21) OP(K,22) OP(K,23) OP(K,24) OP(K,25) OP(K,26) OP(K,27) OP(K,28) OP(K,29) \
    OP(K,30) OP(K,31)
#define REPJH2(OP, K) OP(K,32) OP(K,33) OP(K,34) OP(K,35) OP(K,36) OP(K,37) OP(K,38) OP(K,39) \
    OP(K,40) OP(K,41) OP(K,42) OP(K,43) OP(K,44) OP(K,45) OP(K,46) OP(K,47) OP(K,48) OP(K,49) \
    OP(K,50) OP(K,51) OP(K,52) OP(K,53) OP(K,54) OP(K,55) OP(K,56) OP(K,57) OP(K,58) OP(K,59) \
    OP(K,60) OP(K,61) OP(K,62) OP(K,63)
// 64 (M, Mq=M/4, e=M%4) triples, quarter lists (16-wide batches for TRSM)
#define REPQA(OP, C) OP(C,0,0,0) OP(C,1,0,1) OP(C,2,0,2) OP(C,3,0,3) OP(C,4,1,0) OP(C,5,1,1) OP(C,6,1,2) OP(C,7,1,3) \
    OP(C,8,2,0) OP(C,9,2,1) OP(C,10,2,2) OP(C,11,2,3) OP(C,12,3,0) OP(C,13,3,1) OP(C,14,3,2) OP(C,15,3,3)
#define REPQB(OP, C) OP(C,16,4,0) OP(C,17,4,1) OP(C,18,4,2) OP(C,19,4,3) OP(C,20,5,0) OP(C,21,5,1) OP(C,22,5,2) OP(C,23,5,3) \
    OP(C,24,6,0) OP(C,25,6,1) OP(C,26,6,2) OP(C,27,6,3) OP(C,28,7,0) OP(C,29,7,1) OP(C,30,7,2) OP(C,31,7,3)
#define REPQC(OP, C) OP(C,32,8,0) OP(C,33,8,1) OP(C,34,8,2) OP(C,35,8,3) OP(C,36,9,0) OP(C,37,9,1) OP(C,38,9,2) OP(C,39,9,3) \
    OP(C,40,10,0) OP(C,41,10,1) OP(C,42,10,2) OP(C,43,10,3) OP(C,44,11,0) OP(C,45,11,1) OP(C,46,11,2) OP(C,47,11,3)
#define REPQD(OP, C) OP(C,48,12,0) OP(C,49,12,1) OP(C,50,12,2) OP(C,51,12,3) OP(C,52,13,0) OP(C,53,13,1) OP(C,54,13,2) OP(C,55,13,3) \
    OP(C,56,14,0) OP(C,57,14,1) OP(C,58,14,2) OP(C,59,14,3) OP(C,60,15,0) OP(C,61,15,1) OP(C,62,15,2) OP(C,63,15,3)
#define REPQ(OP, C) REPQA(OP, C) REPQB(OP, C) REPQC(OP, C) REPQD(OP, C)
// 16 (Q, 4Q, 4Q+1, 4Q+2, 4Q+3) groups
#define REPW(OP) OP(0,0,1,2,3) OP(1,4,5,6,7) OP(2,8,9,10,11) OP(3,12,13,14,15) OP(4,16,17,18,19) \
    OP(5,20,21,22,23) OP(6,24,25,26,27) OP(7,28,29,30,31) OP(8,32,33,34,35) OP(9,36,37,38,39) \
    OP(10,40,41,42,43) OP(11,44,45,46,47) OP(12,48,49,50,51) OP(13,52,53,54,55) OP(14,56,57,58,59) \
    OP(15,60,61,62,63)

// ---------------------------------------------------------------------------
// 0) zero mu accumulator (ws is poisoned by harness; atomics need 0-init)
// ---------------------------------------------------------------------------
__global__ __launch_bounds__(256) void k_zero(float* __restrict__ mu) {
    floatx4 z = {0.f, 0.f, 0.f, 0.f};
    ((floatx4*)mu)[blockIdx.x * 256 + threadIdx.x] = z;
}

// ---------------------------------------------------------------------------
// 1) x[b][t][d] (f32) -> Xt[d][b*Tn+t] (bf16), LDS 64x64 tile transpose.
//    Fused per-(b,d) t-sums atomicAdd'ed into mu (mu holds SUMS over t).
// ---------------------------------------------------------------------------
__global__ __launch_bounds__(256) void k_transpose(const float* __restrict__ x,
                                                   u16* __restrict__ Xt,
                                                   float* __restrict__ mu) {
    int tt = blockIdx.x;   // t-tile 0..31
    int dt = blockIdx.y;   // d-tile 0..7
    int b  = blockIdx.z;   // 0..31
    __shared__ u16 sT[64][68];  // [d][t], padded
    int tid = threadIdx.x;
    int row = tid >> 4;            // 0..15 (t)
    int c4  = (tid & 15) * 4;      // 0..60 (d)
    const float* src = x + ((long)b * Tn + (long)tt * 64) * Dn + dt * 64;
#pragma unroll
    for (int q = 0; q < 4; q++) {
        int r = row + q * 16;
        floatx4 v = *(const floatx4*)(src + (long)r * Dn + c4);
        sT[c4 + 0][r] = f2bf(v[0]);
        sT[c4 + 1][r] = f2bf(v[1]);
        sT[c4 + 2][r] = f2bf(v[2]);
        sT[c4 + 3][r] = f2bf(v[3]);
    }
    __syncthreads();
    int drow = tid >> 3;           // 0..31 (d)
    int koff = (tid & 7) * 8;      // 0..56 (t)
    long kout = (long)b * Tn + (long)tt * 64 + koff;
#pragma unroll
    for (int p = 0; p < 2; p++) {
        int dr = drow + p * 32;
        u16 tmp[8];
        float s = 0.f;
#pragma unroll
        for (int j = 0; j < 8; j++) {
            tmp[j] = sT[dr][koff + j];
            s += bf2f(tmp[j]);
        }
        *(short8*)(Xt + (long)(dt * 64 + dr) * BT + kout) = *(short8*)tmp;
        s += __shfl_down(s, 4, 64);
        s += __shfl_down(s, 2, 64);
        s += __shfl_down(s, 1, 64);
        if ((tid & 7) == 0) atomicAdd(mu + b * 512 + dt * 64 + dr, s);
    }
}

// ---------------------------------------------------------------------------
// 2) Gram partials: partial[chunk][d][e] = sum_{k in chunk} Xt[d][k]*Xt[e][k]
// ---------------------------------------------------------------------------
__global__ __launch_bounds__(256, 3) void k_gram(const u16* __restrict__ Xt,
                                                 float* __restrict__ partial) {
    int chunk = blockIdx.x;             // 0..63 (K-chunk of 1024)
    int pos = blockIdx.y;               // 0..9 upper-block-triangle positions
    int di = (pos < 4) ? 0 : (pos < 7) ? 1 : (pos < 9) ? 2 : 3;
    int start = di * 4 - (di * (di - 1)) / 2;   // 0,4,7,9
    int ei = di + (pos - start);
    int d0 = di * 128, e0 = ei * 128;

    __shared__ u16 sA[128 * 32];
    __shared__ u16 sB[128 * 32];
    int tid = threadIdx.x;
    int w = tid >> 6, l = tid & 63;
    int wm = w & 1, wn = w >> 1;        // 2x2 waves over 128x128
    long kbase = (long)chunk * CHUNK_K;
    int srow = w * 16 + (l >> 2);
    int sk = (l & 3) * 8;
    const u16* gA0 = Xt + (long)(d0 + srow) * BT + kbase + sk;
    const u16* gA1 = gA0 + 64l * BT;
    const u16* gB0 = Xt + (long)(e0 + srow) * BT + kbase + sk;
    const u16* gB1 = gB0 + 64l * BT;
    u16* sA0 = sA + (w * 16) * 32;      // wave-uniform LDS bases
    u16* sA1 = sA0 + 64 * 32;
    u16* sB0 = sB + (w * 16) * 32;
    u16* sB1 = sB0 + 64 * 32;
    int m = l & 15, g = l >> 4;
    const u16* fA = sA + (wm * 64 + m) * 32 + g * 8;
    const u16* fB = sB + (wn * 64 + m) * 32 + g * 8;

    floatx4 acc[4][4] = {};
    for (int kk = 0; kk < CHUNK_K; kk += 32) {
        GLL(gA0 + kk, sA0);
        GLL(gA1 + kk, sA1);
        GLL(gB0 + kk, sB0);
        GLL(gB1 + kk, sB1);
        __syncthreads();   // drains vmcnt -> staged data visible
        short8 af[4], bfv[4];
#pragma unroll
        for (int i = 0; i < 4; i++) af[i] = *(const short8*)(fA + i * 16 * 32);
#pragma unroll
        for (int j = 0; j < 4; j++) bfv[j] = *(const short8*)(fB + j * 16 * 32);
#pragma unroll
        for (int i = 0; i < 4; i++)
#pragma unroll
            for (int j = 0; j < 4; j++)
                acc[i][j] = __builtin_amdgcn_mfma_f32_16x16x32_bf16(af[i], bfv[j], acc[i][j], 0, 0, 0);
        __syncthreads();
    }
    float* P = partial + (long)chunk * (512l * 512);
    int col = l & 15, rowg = (l >> 4) * 4;   // C/D: col=lane&15, row=(lane>>4)*4+reg
#pragma unroll
    for (int i = 0; i < 4; i++)
#pragma unroll
        for (int j = 0; j < 4; j++) {
            int rr = d0 + wm * 64 + i * 16 + rowg;
            int cc = e0 + wn * 64 + j * 16 + col;
#pragma unroll
            for (int r = 0; r < 4; r++) P[(long)(rr + r) * 512 + cc] = acc[i][j][r];
        }
}

// ---------------------------------------------------------------------------
// 3) cov assemble (1024 blocks: MLP hides the mirror-read latency; r3 lesson)
// ---------------------------------------------------------------------------
__global__ __launch_bounds__(256) void k_assemble(const float* __restrict__ partial,
                                                  const float* __restrict__ mu,
                                                  float* __restrict__ A) {
    int d = blockIdx.y;
    int e = blockIdx.x * 256 + threadIdx.x;
    int bd = d >> 7, be = e >> 7;
    long idx = (bd <= be) ? ((long)d * 512 + e) : ((long)e * 512 + d);
    float s = 0.f;
#pragma unroll
    for (int c = 0; c < NCHUNK; c++) s += partial[c * (512l * 512) + idx];
    float msum = 0.f;
#pragma unroll
    for (int b = 0; b < 32; b++) msum += mu[b * 512 + d] * mu[b * 512 + e];
    A[(long)d * 512 + e] = (s - msum * (1.0f / Tn)) * (1.0f / ((Tn - 1.0f) * Bn));
}

// ---------------------------------------------------------------------------
// 4a) Cholesky panel, 64 threads (1 wave), nb+1 blocks -- r2 structure with
//     ALL broadcasts via v_readlane (VALU/SALU only; zero LDS/bpermute).
//     Every block factors the 64x64 diag redundantly in named regs; block 0
//     writes the diag back; blocks 1..nb keep r## live and solve one 64-row
//     TRSM stripe, readlane-ing L11[C][M] straight out of r##M lane C.
//     __launch_bounds__(64,1): no VGPR cap -> r##+a## (~150 live) don't spill.
// ---------------------------------------------------------------------------
__global__ __launch_bounds__(64, 1) void k_chol_panel(float* __restrict__ A, int kb) {
    const int k0 = kb * 64;
    const int lane = threadIdx.x;

    // ---- load own diag row into named regs (16 dwordx4, L2-hot) ----
    const float* Dr = A + (long)(k0 + lane) * 512 + k0;
#define LDV(Q,A0,A1,A2,A3) floatx4 v##Q = *(const floatx4*)(Dr + 4*(Q));
    REPW(LDV)
#undef LDV
#define DECR(C,M,Mq,e) float r##M = v##Mq[(e)];
    REPQ(DECR, 0)
#undef DECR

    // ---- factor: 64 steps; per step, halved readlane batch then fma batch ----
    float vinv = 0.f;
#define SH1(K,J) float t##J = ((J) > (K)) ? RLF(lik, J) : 0.0f;
#define FM1(K,J) if ((J) > (K)) r##J = fmaf(nlik, t##J, r##J);
#define STEP(K) { float akk = RLF(r##K, K); float sd = sqrtf(akk); \
                  float inv = 1.0f / sd; float lik = (lane == (K)) ? sd : r##K * inv; \
                  r##K = lik; if (lane == (K)) vinv = inv; float nlik = -lik; \
                  { REPJH1(SH1, K) REPJH1(FM1, K) } { REPJH2(SH1, K) REPJH2(FM1, K) } }
    REP64(STEP)
#undef STEP
#undef FM1
#undef SH1

    if (blockIdx.x == 0) {
        // write back factored diag (junk upper triangle never read downstream)
        float* W = A + (long)(k0 + lane) * 512 + k0;
#define STW(Q,A0,A1,A2,A3) { floatx4 w; w[0]=r##A0; w[1]=r##A1; w[2]=r##A2; w[3]=r##A3; \
                             *(floatx4*)(W + 4*(Q)) = w; }
        REPW(STW)
#undef STW
        return;
    }

    // ---- TRSM: lane = row of this block's 64-row stripe; L11 via readlane ----
    int rbase = k0 + 64 + (blockIdx.x - 1) * 64;
    const float* R = A + (long)(rbase + lane) * 512 + k0;
#define LDA(Q,A0,A1,A2,A3) floatx4 u##Q = *(const floatx4*)(R + 4*(Q));
    REPW(LDA)
#undef LDA
#define DECA(C,M,Mq,e) float a##M = u##Mq[(e)];
    REPQ(DECA, 0)
#undef DECA
    // step C: a_C = (a_C - sum_{M<C} a_M * L11[C][M]) * inv_C
    //         L11[C][M] = readlane(r_M, C);  inv_C = readlane(vinv, C)
#define TRL(C,M,Mq,e) float t##M = ((M) < (C)) ? RLF(r##M, C) : 0.0f;
#define TFM(C,M,Mq,e) if ((M) < (C)) acc##e = fmaf(a##M, t##M, acc##e);
#define TSTEP(C) { float acc0 = 0.f, acc1 = 0.f, acc2 = 0.f, acc3 = 0.f; \
                   { REPQA(TRL, C) REPQA(TFM, C) } { REPQB(TRL, C) REPQB(TFM, C) } \
                   { REPQC(TRL, C) REPQC(TFM, C) } { REPQD(TRL, C) REPQD(TFM, C) } \
                   float invC = RLF(vinv, C); \
                   a##C = (a##C - ((acc0 + acc1) + (acc2 + acc3))) * invC; }
    REP64(TSTEP)
#undef TSTEP
#undef TFM
#undef TRL

    float* Wr = A + (long)(rbase + lane) * 512 + k0;
#define STA(Q,A0,A1,A2,A3) { floatx4 w; w[0]=a##A0; w[1]=a##A1; w[2]=a##A2; w[3]=a##A3; \
                             *(floatx4*)(Wr + 4*(Q)) = w; }
    REPW(STA)
#undef STA
}

// ---------------------------------------------------------------------------
// 4b) Trailing update: A22 -= L21 * L21^T, one 64x64 tile per block (fp32).
// ---------------------------------------------------------------------------
__global__ __launch_bounds__(256) void k_chol_update(float* __restrict__ A, int kb) {
    int k0 = kb * 64, base = k0 + 64;
    int idx = blockIdx.x, ti = 0;
    while (idx > ti) { idx -= ti + 1; ti++; }
    int tj = idx;
    int r0 = base + ti * 64, c0 = base + tj * 64;
    __shared__ float sI[64][65];
    __shared__ float sJ[64][65];
    int tid = threadIdx.x;
    int row = tid >> 4, c4 = (tid & 15) * 4;
#pragma unroll
    for (int q = 0; q < 4; q++) {
        int rr = row + q * 16;
        *(floatx4*)&sI[rr][c4] = *(const floatx4*)(A + (long)(r0 + rr) * 512 + k0 + c4);
        *(floatx4*)&sJ[rr][c4] = *(const floatx4*)(A + (long)(c0 + rr) * 512 + k0 + c4);
    }
    __syncthreads();
    int ri = (tid >> 4) * 4, cj = (tid & 15) * 4;
    float acc[4][4] = {};
    for (int k = 0; k < 64; k += 4) {
        floatx4 av[4], bv[4];
#pragma unroll
        for (int ii = 0; ii < 4; ii++) av[ii] = *(const floatx4*)&sI[ri + ii][k];
#pragma unroll
        for (int jj = 0; jj < 4; jj++) bv[jj] = *(const floatx4*)&sJ[cj + jj][k];
#pragma unroll
        for (int ii = 0; ii < 4; ii++)
#pragma unroll
            for (int jj = 0; jj < 4; jj++)
#pragma unroll
                for (int q = 0; q < 4; q++)
                    acc[ii][jj] = fmaf(av[ii][q], bv[jj][q], acc[ii][jj]);
    }
#pragma unroll
    for (int ii = 0; ii < 4; ii++) {
        float* dst = A + (long)(r0 + ri + ii) * 512 + c0 + cj;
        floatx4 old = *(const floatx4*)dst;
#pragma unroll
        for (int jj = 0; jj < 4; jj++) old[jj] -= acc[ii][jj];
        *(floatx4*)dst = old;
    }
}

// ---------------------------------------------------------------------------
// 5) out[i][d] = mean[d] + sum_{e<=d} z[i][e] * L[d][e]
//    mu holds t-SUMS: mean[d] = sum_b mu[b,d] / (B*T)
// ---------------------------------------------------------------------------
__global__ __launch_bounds__(512) void k_output(const float* __restrict__ z,
                                                const float* __restrict__ A,
                                                const float* __restrict__ mu,
                                                float* __restrict__ out) {
    int i = blockIdx.x, d = threadIdx.x;
    __shared__ float sz[512];
    sz[d] = z[(long)i * 512 + d];
    __syncthreads();
    float mean = 0.f;
#pragma unroll
    for (int b = 0; b < 32; b++) mean += mu[b * 512 + d];
    mean *= (1.0f / (32.0f * 2048.0f));
    const float* Lr = A + (long)d * 512;
    float acc = 0.f;
    int dmax = d + 1;
    int e4 = dmax & ~3;
    for (int e = 0; e < e4; e += 4) {
        floatx4 l = *(const floatx4*)(Lr + e);
        acc += l[0] * sz[e] + l[1] * sz[e + 1] + l[2] * sz[e + 2] + l[3] * sz[e + 3];
    }
    for (int e = e4; e < dmax; e++) acc += Lr[e] * sz[e];
    out[(long)i * 512 + d] = mean + acc;
}

// ---------------------------------------------------------------------------
extern "C" void kernel_launch(void* const* d_in, const int* in_sizes, int n_in,
                              void* d_out, int out_size, void* d_ws, size_t ws_size,
                              hipStream_t stream) {
    const float* x = (const float*)d_in[0];
    const float* z = (const float*)d_in[1];
    float* out = (float*)d_out;
    char* ws = (char*)d_ws;
    // ws layout: Xt 67108864 | mu 65536 | partial 67108864 | A 1048576
    u16* Xt = (u16*)ws;
    float* mu = (float*)(ws + 67108864);
    float* partial = (float*)(ws + 67108864 + 65536);
    float* A = (float*)(ws + 67108864 + 65536 + 67108864);

    k_zero<<<16, 256, 0, stream>>>(mu);
    k_transpose<<<dim3(32, 8, 32), 256, 0, stream>>>(x, Xt, mu);
    k_gram<<<dim3(NCHUNK, 10), 256, 0, stream>>>(Xt, partial);
    k_assemble<<<dim3(2, 512), 256, 0, stream>>>(partial, mu, A);
    for (int kb = 0; kb < 8; kb++) {
        int nb = 7 - kb;                 // 64-row stripes below the diagonal
        k_chol_panel<<<nb + 1, 64, 0, stream>>>(A, kb);
        int tiles = nb * (nb + 1) / 2;
        if (tiles > 0) k_chol_update<<<tiles, 256, 0, stream>>>(A, kb);
    }
    k_output<<<32, 512, 0, stream>>>(z, A, mu, out);
}

// Round 10
// 558.542 us; speedup vs baseline: 3.3137x; 1.0292x over previous
//
#include <hip/hip_runtime.h>

#define Dn 512
#define Bn 32
#define Tn 2048
#define BT 65536   // Bn*Tn
#define NCHUNK 64  // K-chunks for gram (64*10 = 640 blocks ~ 2.5/CU)
#define CHUNK_K 1024  // 65536/64

typedef unsigned short u16;
typedef __attribute__((ext_vector_type(8))) short short8;   // 8 bf16 = 4 VGPRs (MFMA A/B frag)
typedef __attribute__((ext_vector_type(4))) float floatx4;  // MFMA C/D frag

__device__ __forceinline__ u16 f2bf(float f) {
    unsigned u = __float_as_uint(f);
    unsigned r = (u + 0x7FFFu + ((u >> 16) & 1u)) >> 16;    // RNE
    return (u16)r;
}
__device__ __forceinline__ float bf2f(u16 s) { return __uint_as_float(((unsigned)s) << 16); }

// async global->LDS, 16B per lane; LDS dest is wave-uniform base + lane*16 (m104)
#define GLL(gp, sp) __builtin_amdgcn_global_load_lds( \
    (const __attribute__((address_space(1))) void*)(gp), \
    (__attribute__((address_space(3))) void*)(sp), 16, 0, 0)

// Uniform broadcast from a compile-time lane: v_readlane -> SGPR, consumed as
// the single allowed SGPR operand of v_fma. NO LDS pipe, no ds_bpermute.
// (r8-proven: chol chain shfl->readlane = 665->575 total.)
#define RLF(x, L) __uint_as_float(__builtin_amdgcn_readlane(__float_as_uint(x), (L)))

// Repeat lists (named scalars, not arrays -> no scratch).
// NAMESPACE WARNING (r9 bug): these macros declare identifiers r0..r63,
// a0..a63, t0..t63, u0..u15, v0..v15, acc0..3 -- enclosing scopes must NOT
// use any colliding names (r9's `int r0` tile base was silently shadowed by
// `float r0` -> float->int sbase garbage -> absmax 3.6).
#define REP64(X) X(0) X(1) X(2) X(3) X(4) X(5) X(6) X(7) X(8) X(9) X(10) X(11) X(12) X(13) X(14) X(15) \
    X(16) X(17) X(18) X(19) X(20) X(21) X(22) X(23) X(24) X(25) X(26) X(27) X(28) X(29) X(30) X(31) \
    X(32) X(33) X(34) X(35) X(36) X(37) X(38) X(39) X(40) X(41) X(42) X(43) X(44) X(45) X(46) X(47) \
    X(48) X(49) X(50) X(51) X(52) X(53) X(54) X(55) X(56) X(57) X(58) X(59) X(60) X(61) X(62) X(63)
// halves of 0..63 (factor broadcast batches; bounds SGPR temp liveness to 32)
#define REPJH1(OP, K) OP(K,0) OP(K,1) OP(K,2) OP(K,3) OP(K,4) OP(K,5) OP(K,6) OP(K,7) OP(K,8) OP(K,9) \
    OP(K,10) OP(K,11) OP(K,12) OP(K,13) OP(K,14) OP(K,15) OP(K,16) OP(K,17) OP(K,18) OP(K,19) \
    OP(K,20) OP(K,21) OP(K,22) OP(K,23) OP(K,24) OP(K,25) OP(K,26) OP(K,27) OP(K,28) OP(K,29) \
    OP(K,30) OP(K,31)
#define REPJH2(OP, K) OP(K,32) OP(K,33) OP(K,34) OP(K,35) OP(K,36) OP(K,37) OP(K,38) OP(K,39) \
    OP(K,40) OP(K,41) OP(K,42) OP(K,43) OP(K,44) OP(K,45) OP(K,46) OP(K,47) OP(K,48) OP(K,49) \
    OP(K,50) OP(K,51) OP(K,52) OP(K,53) OP(K,54) OP(K,55) OP(K,56) OP(K,57) OP(K,58) OP(K,59) \
    OP(K,60) OP(K,61) OP(K,62) OP(K,63)
// 64 (M, Mq=M/4, e=M%4) triples, quarter lists (16-wide batches for TRSM)
#define REPQA(OP, C) OP(C,0,0,0) OP(C,1,0,1) OP(C,2,0,2) OP(C,3,0,3) OP(C,4,1,0) OP(C,5,1,1) OP(C,6,1,2) OP(C,7,1,3) \
    OP(C,8,2,0) OP(C,9,2,1) OP(C,10,2,2) OP(C,11,2,3) OP(C,12,3,0) OP(C,13,3,1) OP(C,14,3,2) OP(C,15,3,3)
#define REPQB(OP, C) OP(C,16,4,0) OP(C,17,4,1) OP(C,18,4,2) OP(C,19,4,3) OP(C,20,5,0) OP(C,21,5,1) OP(C,22,5,2) OP(C,23,5,3) \
    OP(C,24,6,0) OP(C,25,6,1) OP(C,26,6,2) OP(C,27,6,3) OP(C,28,7,0) OP(C,29,7,1) OP(C,30,7,2) OP(C,31,7,3)
#define REPQC(OP, C) OP(C,32,8,0) OP(C,33,8,1) OP(C,34,8,2) OP(C,35,8,3) OP(C,36,9,0) OP(C,37,9,1) OP(C,38,9,2) OP(C,39,9,3) \
    OP(C,40,10,0) OP(C,41,10,1) OP(C,42,10,2) OP(C,43,10,3) OP(C,44,11,0) OP(C,45,11,1) OP(C,46,11,2) OP(C,47,11,3)
#define REPQD(OP, C) OP(C,48,12,0) OP(C,49,12,1) OP(C,50,12,2) OP(C,51,12,3) OP(C,52,13,0) OP(C,53,13,1) OP(C,54,13,2) OP(C,55,13,3) \
    OP(C,56,14,0) OP(C,57,14,1) OP(C,58,14,2) OP(C,59,14,3) OP(C,60,15,0) OP(C,61,15,1) OP(C,62,15,2) OP(C,63,15,3)
#define REPQ(OP, C) REPQA(OP, C) REPQB(OP, C) REPQC(OP, C) REPQD(OP, C)
// 16 (Q, 4Q, 4Q+1, 4Q+2, 4Q+3) groups
#define REPW(OP) OP(0,0,1,2,3) OP(1,4,5,6,7) OP(2,8,9,10,11) OP(3,12,13,14,15) OP(4,16,17,18,19) \
    OP(5,20,21,22,23) OP(6,24,25,26,27) OP(7,28,29,30,31) OP(8,32,33,34,35) OP(9,36,37,38,39) \
    OP(10,40,41,42,43) OP(11,44,45,46,47) OP(12,48,49,50,51) OP(13,52,53,54,55) OP(14,56,57,58,59) \
    OP(15,60,61,62,63)

// ---------------------------------------------------------------------------
// 0) zero mu accumulator (ws is poisoned by harness; atomics need 0-init)
// ---------------------------------------------------------------------------
__global__ __launch_bounds__(256) void k_zero(float* __restrict__ mu) {
    floatx4 z = {0.f, 0.f, 0.f, 0.f};
    ((floatx4*)mu)[blockIdx.x * 256 + threadIdx.x] = z;
}

// ---------------------------------------------------------------------------
// 1) x[b][t][d] (f32) -> Xt[d][b*Tn+t] (bf16), LDS 64x64 tile transpose.
//    Fused per-(b,d) t-sums atomicAdd'ed into mu (mu holds SUMS over t).
// ---------------------------------------------------------------------------
__global__ __launch_bounds__(256) void k_transpose(const float* __restrict__ x,
                                                   u16* __restrict__ Xt,
                                                   float* __restrict__ mu) {
    int tt = blockIdx.x;   // t-tile 0..31
    int dt = blockIdx.y;   // d-tile 0..7
    int b  = blockIdx.z;   // 0..31
    __shared__ u16 sT[64][68];  // [d][t], padded
    int tid = threadIdx.x;
    int row = tid >> 4;            // 0..15 (t)
    int c4  = (tid & 15) * 4;      // 0..60 (d)
    const float* src = x + ((long)b * Tn + (long)tt * 64) * Dn + dt * 64;
#pragma unroll
    for (int q = 0; q < 4; q++) {
        int r = row + q * 16;
        floatx4 v = *(const floatx4*)(src + (long)r * Dn + c4);
        sT[c4 + 0][r] = f2bf(v[0]);
        sT[c4 + 1][r] = f2bf(v[1]);
        sT[c4 + 2][r] = f2bf(v[2]);
        sT[c4 + 3][r] = f2bf(v[3]);
    }
    __syncthreads();
    int drow = tid >> 3;           // 0..31 (d)
    int koff = (tid & 7) * 8;      // 0..56 (t)
    long kout = (long)b * Tn + (long)tt * 64 + koff;
#pragma unroll
    for (int p = 0; p < 2; p++) {
        int dr = drow + p * 32;
        u16 tmp[8];
        float s = 0.f;
#pragma unroll
        for (int j = 0; j < 8; j++) {
            tmp[j] = sT[dr][koff + j];
            s += bf2f(tmp[j]);
        }
        *(short8*)(Xt + (long)(dt * 64 + dr) * BT + kout) = *(short8*)tmp;
        s += __shfl_down(s, 4, 64);
        s += __shfl_down(s, 2, 64);
        s += __shfl_down(s, 1, 64);
        if ((tid & 7) == 0) atomicAdd(mu + b * 512 + dt * 64 + dr, s);
    }
}

// ---------------------------------------------------------------------------
// 2) Gram partials: partial[chunk][d][e] = sum_{k in chunk} Xt[d][k]*Xt[e][k]
// ---------------------------------------------------------------------------
__global__ __launch_bounds__(256, 3) void k_gram(const u16* __restrict__ Xt,
                                                 float* __restrict__ partial) {
    int chunk = blockIdx.x;             // 0..63 (K-chunk of 1024)
    int pos = blockIdx.y;               // 0..9 upper-block-triangle positions
    int di = (pos < 4) ? 0 : (pos < 7) ? 1 : (pos < 9) ? 2 : 3;
    int start = di * 4 - (di * (di - 1)) / 2;   // 0,4,7,9
    int ei = di + (pos - start);
    int d0 = di * 128, e0 = ei * 128;

    __shared__ u16 sA[128 * 32];
    __shared__ u16 sB[128 * 32];
    int tid = threadIdx.x;
    int w = tid >> 6, l = tid & 63;
    int wm = w & 1, wn = w >> 1;        // 2x2 waves over 128x128
    long kbase = (long)chunk * CHUNK_K;
    int srow = w * 16 + (l >> 2);
    int sk = (l & 3) * 8;
    const u16* gA0 = Xt + (long)(d0 + srow) * BT + kbase + sk;
    const u16* gA1 = gA0 + 64l * BT;
    const u16* gB0 = Xt + (long)(e0 + srow) * BT + kbase + sk;
    const u16* gB1 = gB0 + 64l * BT;
    u16* sA0 = sA + (w * 16) * 32;      // wave-uniform LDS bases
    u16* sA1 = sA0 + 64 * 32;
    u16* sB0 = sB + (w * 16) * 32;
    u16* sB1 = sB0 + 64 * 32;
    int m = l & 15, g = l >> 4;
    const u16* fA = sA + (wm * 64 + m) * 32 + g * 8;
    const u16* fB = sB + (wn * 64 + m) * 32 + g * 8;

    floatx4 acc[4][4] = {};
    for (int kk = 0; kk < CHUNK_K; kk += 32) {
        GLL(gA0 + kk, sA0);
        GLL(gA1 + kk, sA1);
        GLL(gB0 + kk, sB0);
        GLL(gB1 + kk, sB1);
        __syncthreads();   // drains vmcnt -> staged data visible
        short8 af[4], bfv[4];
#pragma unroll
        for (int i = 0; i < 4; i++) af[i] = *(const short8*)(fA + i * 16 * 32);
#pragma unroll
        for (int j = 0; j < 4; j++) bfv[j] = *(const short8*)(fB + j * 16 * 32);
#pragma unroll
        for (int i = 0; i < 4; i++)
#pragma unroll
            for (int j = 0; j < 4; j++)
                acc[i][j] = __builtin_amdgcn_mfma_f32_16x16x32_bf16(af[i], bfv[j], acc[i][j], 0, 0, 0);
        __syncthreads();
    }
    float* P = partial + (long)chunk * (512l * 512);
    int col = l & 15, rowg = (l >> 4) * 4;   // C/D: col=lane&15, row=(lane>>4)*4+reg
#pragma unroll
    for (int i = 0; i < 4; i++)
#pragma unroll
        for (int j = 0; j < 4; j++) {
            int rr = d0 + wm * 64 + i * 16 + rowg;
            int cc = e0 + wn * 64 + j * 16 + col;
#pragma unroll
            for (int r = 0; r < 4; r++) P[(long)(rr + r) * 512 + cc] = acc[i][j][r];
        }
}

// ---------------------------------------------------------------------------
// 3) cov assemble (1024 blocks: MLP hides the mirror-read latency; r3 lesson)
// ---------------------------------------------------------------------------
__global__ __launch_bounds__(256) void k_assemble(const float* __restrict__ partial,
                                                  const float* __restrict__ mu,
                                                  float* __restrict__ A) {
    int d = blockIdx.y;
    int e = blockIdx.x * 256 + threadIdx.x;
    int bd = d >> 7, be = e >> 7;
    long idx = (bd <= be) ? ((long)d * 512 + e) : ((long)e * 512 + d);
    float s = 0.f;
#pragma unroll
    for (int c = 0; c < NCHUNK; c++) s += partial[c * (512l * 512) + idx];
    float msum = 0.f;
#pragma unroll
    for (int b = 0; b < 32; b++) msum += mu[b * 512 + d] * mu[b * 512 + e];
    A[(long)d * 512 + e] = (s - msum * (1.0f / Tn)) * (1.0f / ((Tn - 1.0f) * Bn));
}

// ---------------------------------------------------------------------------
// 4) MERGED Cholesky step kb (one launch per kb, 7 launches + final factor):
//    grid = tiles(kb) = nb(nb+1)/2 blocks x 256 thr. Each block OWNS one
//    trailing 64x64 update tile (ti,tj) and REDUNDANTLY computes the panel it
//    needs: waves 0,1 each factor the diag via readlane (r8-proven), then IN
//    PARALLEL TRSM stripe ti (wave0 -> sI) and stripe tj (wave1 -> sJ); all
//    256 threads then run the r2-proven LDS 4x4 update on tile (row0,col0).
//    Factored L goes to SEPARATE Lmat (A keeps raw values) => no block reads
//    anything another block writes this launch: race-free without grid sync.
//    r9 FIX: tile bases renamed row0/col0 (int r0 was shadowed by macro
//    float r0 -> float->int garbage sbase).
// ---------------------------------------------------------------------------
__global__ __launch_bounds__(256, 1) void k_chol_step(float* __restrict__ A,
                                                      float* __restrict__ L,
                                                      int kb) {
    const int k0 = kb * 64;
    const int tid = threadIdx.x;
    const int lane = tid & 63;
    const int wave = tid >> 6;
    int idx = blockIdx.x, ti = 0;
    while (idx > ti) { idx -= ti + 1; ti++; }
    const int tj = idx;
    const int row0 = k0 + 64 + ti * 64;
    const int col0 = k0 + 64 + tj * 64;
    __shared__ float sI[64 * 65];
    __shared__ float sJ[64 * 65];

    if (wave < 2) {
        // ---- factor diag redundantly in named regs (readlane broadcasts) ----
        const float* Dr = A + (long)(k0 + lane) * 512 + k0;
#define LDV(Q,A0,A1,A2,A3) floatx4 v##Q = *(const floatx4*)(Dr + 4*(Q));
        REPW(LDV)
#undef LDV
#define DECR(C,M,Mq,e) float r##M = v##Mq[(e)];
        REPQ(DECR, 0)
#undef DECR
        float vinv = 0.f;
#define SH1(K,J) float t##J = ((J) > (K)) ? RLF(lik, J) : 0.0f;
#define FM1(K,J) if ((J) > (K)) r##J = fmaf(nlik, t##J, r##J);
#define STEP(K) { float akk = RLF(r##K, K); float sd = sqrtf(akk); \
                  float inv = 1.0f / sd; float lik = (lane == (K)) ? sd : r##K * inv; \
                  r##K = lik; if (lane == (K)) vinv = inv; float nlik = -lik; \
                  { REPJH1(SH1, K) REPJH1(FM1, K) } { REPJH2(SH1, K) REPJH2(FM1, K) } }
        REP64(STEP)
#undef STEP
#undef FM1
#undef SH1
        if (blockIdx.x == 0 && wave == 0) {
            // factored diag -> Lmat (junk upper-within-tile never read)
            float* W = L + (long)(k0 + lane) * 512 + k0;
#define STW(Q,A0,A1,A2,A3) { floatx4 w; w[0]=r##A0; w[1]=r##A1; w[2]=r##A2; w[3]=r##A3; \
                             *(floatx4*)(W + 4*(Q)) = w; }
            REPW(STW)
#undef STW
        }

        // ---- TRSM own stripe: wave0 -> rows row0 (sI), wave1 -> col0 (sJ) ----
        const int sbase = (wave == 0) ? row0 : col0;
        const float* R = A + (long)(sbase + lane) * 512 + k0;
#define LDA(Q,A0,A1,A2,A3) floatx4 u##Q = *(const floatx4*)(R + 4*(Q));
        REPW(LDA)
#undef LDA
#define DECA(C,M,Mq,e) float a##M = u##Mq[(e)];
        REPQ(DECA, 0)
#undef DECA
#define TRL(C,M,Mq,e) float t##M = ((M) < (C)) ? RLF(r##M, C) : 0.0f;
#define TFM(C,M,Mq,e) if ((M) < (C)) acc##e = fmaf(a##M, t##M, acc##e);
#define TSTEP(C) { float acc0 = 0.f, acc1 = 0.f, acc2 = 0.f, acc3 = 0.f; \
                   { REPQA(TRL, C) REPQA(TFM, C) } { REPQB(TRL, C) REPQB(TFM, C) } \
                   { REPQC(TRL, C) REPQC(TFM, C) } { REPQD(TRL, C) REPQD(TFM, C) } \
                   float invC = RLF(vinv, C); \
                   a##C = (a##C - ((acc0 + acc1) + (acc2 + acc3))) * invC; }
        REP64(TSTEP)
#undef TSTEP
#undef TFM
#undef TRL
        // stage solved stripe rows to LDS for the update
        float* sS = (wave == 0) ? sI : sJ;
#define STS(Q,A0,A1,A2,A3) { floatx4 w; w[0]=a##A0; w[1]=a##A1; w[2]=a##A2; w[3]=a##A3; \
                             *(floatx4*)(sS + lane * 65 + 4*(Q)) = w; }
        REPW(STS)
#undef STS
        // block (t,t) / wave0: write solved stripe t to Lmat
        if (ti == tj && wave == 0) {
            float* Wr = L + (long)(row0 + lane) * 512 + k0;
#define STA(Q,A0,A1,A2,A3) { floatx4 w; w[0]=a##A0; w[1]=a##A1; w[2]=a##A2; w[3]=a##A3; \
                             *(floatx4*)(Wr + 4*(Q)) = w; }
            REPW(STA)
#undef STA
        }
    }
    __syncthreads();

    // ---- 256-thread LDS update: A(row0,col0) -= SI * SJ^T (r2-proven) ----
    {
        int ri = (tid >> 4) * 4, cj = (tid & 15) * 4;
        float acc[4][4] = {};
        for (int k = 0; k < 64; k += 4) {
            floatx4 av[4], bv[4];
#pragma unroll
            for (int ii = 0; ii < 4; ii++) av[ii] = *(const floatx4*)&sI[(ri + ii) * 65 + k];
#pragma unroll
            for (int jj = 0; jj < 4; jj++) bv[jj] = *(const floatx4*)&sJ[(cj + jj) * 65 + k];
#pragma unroll
            for (int ii = 0; ii < 4; ii++)
#pragma unroll
                for (int jj = 0; jj < 4; jj++)
#pragma unroll
                    for (int q = 0; q < 4; q++)
                        acc[ii][jj] = fmaf(av[ii][q], bv[jj][q], acc[ii][jj]);
        }
#pragma unroll
        for (int ii = 0; ii < 4; ii++) {
            float* dst = A + (long)(row0 + ri + ii) * 512 + col0 + cj;
            floatx4 old = *(const floatx4*)dst;
#pragma unroll
            for (int jj = 0; jj < 4; jj++) old[jj] -= acc[ii][jj];
            *(floatx4*)dst = old;
        }
    }
}

// ---------------------------------------------------------------------------
// 4b) Final diag factor (kb=7): 1 block, 1 wave, factor + write to Lmat.
// ---------------------------------------------------------------------------
__global__ __launch_bounds__(64, 1) void k_chol_last(const float* __restrict__ A,
                                                     float* __restrict__ L) {
    const int k0 = 7 * 64;
    const int lane = threadIdx.x;
    const float* Dr = A + (long)(k0 + lane) * 512 + k0;
#define LDV(Q,A0,A1,A2,A3) floatx4 v##Q = *(const floatx4*)(Dr + 4*(Q));
    REPW(LDV)
#undef LDV
#define DECR(C,M,Mq,e) float r##M = v##Mq[(e)];
    REPQ(DECR, 0)
#undef DECR
#define SH1(K,J) float t##J = ((J) > (K)) ? RLF(lik, J) : 0.0f;
#define FM1(K,J) if ((J) > (K)) r##J = fmaf(nlik, t##J, r##J);
#define STEP(K) { float akk = RLF(r##K, K); float sd = sqrtf(akk); \
                  float inv = 1.0f / sd; float lik = (lane == (K)) ? sd : r##K * inv; \
                  r##K = lik; float nlik = -lik; \
                  { REPJH1(SH1, K) REPJH1(FM1, K) } { REPJH2(SH1, K) REPJH2(FM1, K) } }
    REP64(STEP)
#undef STEP
#undef FM1
#undef SH1
    float* W = L + (long)(k0 + lane) * 512 + k0;
#define STW(Q,A0,A1,A2,A3) { floatx4 w; w[0]=r##A0; w[1]=r##A1; w[2]=r##A2; w[3]=r##A3; \
                             *(floatx4*)(W + 4*(Q)) = w; }
    REPW(STW)
#undef STW
}

// ---------------------------------------------------------------------------
// 5) out[i][d] = mean[d] + sum_{e<=d} z[i][e] * L[d][e]   (L = Lmat)
//    mu holds t-SUMS: mean[d] = sum_b mu[b,d] / (B*T)
// ---------------------------------------------------------------------------
__global__ __launch_bounds__(512) void k_output(const float* __restrict__ z,
                                                const float* __restrict__ L,
                                                const float* __restrict__ mu,
                                                float* __restrict__ out) {
    int i = blockIdx.x, d = threadIdx.x;
    __shared__ float sz[512];
    sz[d] = z[(long)i * 512 + d];
    __syncthreads();
    float mean = 0.f;
#pragma unroll
    for (int b = 0; b < 32; b++) mean += mu[b * 512 + d];
    mean *= (1.0f / (32.0f * 2048.0f));
    const float* Lr = L + (long)d * 512;
    float acc = 0.f;
    int dmax = d + 1;
    int e4 = dmax & ~3;
    for (int e = 0; e < e4; e += 4) {
        floatx4 l = *(const floatx4*)(Lr + e);
        acc += l[0] * sz[e] + l[1] * sz[e + 1] + l[2] * sz[e + 2] + l[3] * sz[e + 3];
    }
    for (int e = e4; e < dmax; e++) acc += Lr[e] * sz[e];
    out[(long)i * 512 + d] = mean + acc;
}

// ---------------------------------------------------------------------------
extern "C" void kernel_launch(void* const* d_in, const int* in_sizes, int n_in,
                              void* d_out, int out_size, void* d_ws, size_t ws_size,
                              hipStream_t stream) {
    const float* x = (const float*)d_in[0];
    const float* z = (const float*)d_in[1];
    float* out = (float*)d_out;
    char* ws = (char*)d_ws;
    // ws layout: Xt 67108864 | mu 65536 | partial 67108864 | A 1048576 | Lmat 1048576
    u16* Xt = (u16*)ws;
    float* mu = (float*)(ws + 67108864);
    float* partial = (float*)(ws + 67108864 + 65536);
    float* A = (float*)(ws + 67108864 + 65536 + 67108864);
    float* Lmat = (float*)(ws + 67108864 + 65536 + 67108864 + 1048576);

    k_zero<<<16, 256, 0, stream>>>(mu);
    k_transpose<<<dim3(32, 8, 32), 256, 0, stream>>>(x, Xt, mu);
    k_gram<<<dim3(NCHUNK, 10), 256, 0, stream>>>(Xt, partial);
    k_assemble<<<dim3(2, 512), 256, 0, stream>>>(partial, mu, A);
    for (int kb = 0; kb < 7; kb++) {
        int nb = 7 - kb;
        k_chol_step<<<nb * (nb + 1) / 2, 256, 0, stream>>>(A, Lmat, kb);
    }
    k_chol_last<<<1, 64, 0, stream>>>(A, Lmat);
    k_output<<<32, 512, 0, stream>>>(z, Lmat, mu, out);
}